// Round 1
// baseline (6274.842 us; speedup 1.0000x reference)
//
#include <hip/hip_runtime.h>
#include <stdint.h>

#define B_ 8
#define T_ 32
#define N_ 2048
#define C_ 64

typedef __attribute__((ext_vector_type(4))) float f32x4;
typedef __attribute__((ext_vector_type(8))) short s16x8;
typedef __attribute__((ext_vector_type(4))) short s16x4;

static __device__ __forceinline__ unsigned short f2bf(float f){
  union { float f; unsigned u; } v; v.f = f;
  unsigned u = v.u;
  return (unsigned short)((u + 0x7FFFu + ((u >> 16) & 1u)) >> 16);
}
static __device__ __forceinline__ float bf2f(unsigned short h){
  union { unsigned u; float f; } v; v.u = ((unsigned)h) << 16;
  return v.f;
}
static __device__ __forceinline__ float sigmoidf_(float x){
  return 1.f / (1.f + __expf(-x));
}

// ---------------- prep ----------------
__global__ __launch_bounds__(256) void k_prep_A(const float* __restrict__ A,
                                                unsigned short* __restrict__ Abf){
  int i = blockIdx.x * 256 + threadIdx.x;       // float4 index, 1048576 total
  float4 v = ((const float4*)A)[i];
  s16x4 o;
  o[0] = (short)f2bf(v.x); o[1] = (short)f2bf(v.y);
  o[2] = (short)f2bf(v.z); o[3] = (short)f2bf(v.w);
  ((s16x4*)Abf)[i] = o;
}

// wA = w0 - w2, wB = -w1, wC = 2*w2   (each 64x64 f32)
__global__ __launch_bounds__(256) void k_prep_w(const float* __restrict__ chw,
                                                float* __restrict__ wABC){
  int i = blockIdx.x * 256 + threadIdx.x;       // 0..4095
  float a = chw[i], b = chw[4096 + i], c = chw[8192 + i];
  wABC[i]        = a - c;
  wABC[4096 + i] = -b;
  wABC[8192 + i] = 2.f * c;
}

// ---------------- conv main-loop (shared by conv1/conv2) ----------------
static __device__ __forceinline__ void conv_main(
    const unsigned short lx[3][32][72], const float* __restrict__ w,
    int s, int co0, float acc[16])
{
  for (int kt = 0; kt < 3; ++kt){
    const float* wk = w + kt * 64 * 128 + co0;
    #pragma unroll 2
    for (int c8 = 0; c8 < 64; c8 += 8){
      s16x8 xv8 = *(const s16x8*)&lx[kt][s][c8];
      #pragma unroll
      for (int j = 0; j < 8; ++j){
        float xv = bf2f((unsigned short)xv8[j]);
        const float* wr = wk + (c8 + j) * 128;
        float4 w0 = *(const float4*)(wr);
        float4 w1 = *(const float4*)(wr + 4);
        float4 w2 = *(const float4*)(wr + 8);
        float4 w3 = *(const float4*)(wr + 12);
        acc[0]  += xv * w0.x; acc[1]  += xv * w0.y; acc[2]  += xv * w0.z; acc[3]  += xv * w0.w;
        acc[4]  += xv * w1.x; acc[5]  += xv * w1.y; acc[6]  += xv * w1.z; acc[7]  += xv * w1.w;
        acc[8]  += xv * w2.x; acc[9]  += xv * w2.y; acc[10] += xv * w2.z; acc[11] += xv * w2.w;
        acc[12] += xv * w3.x; acc[13] += xv * w3.y; acc[14] += xv * w3.z; acc[15] += xv * w3.w;
      }
    }
  }
}

// ---------------- conv1 + GLU -> h1 (bf16) and h1T (bf16, [bt][c][n]) ----------------
__global__ __launch_bounds__(256) void k_conv1(
    const float* __restrict__ x, const float* __restrict__ w,
    const float* __restrict__ bias,
    unsigned short* __restrict__ h1, unsigned short* __restrict__ h1T)
{
  __shared__ unsigned short lx[3][32][72];
  __shared__ unsigned short shh[32][72];
  const int tid = threadIdx.x;
  const int bt = blockIdx.y, t = bt & 31;
  const int n0 = blockIdx.x * 32;

  #pragma unroll
  for (int k = 0; k < 24; ++k){
    int idx = tid + k * 256;
    int kt = idx >> 11;
    int r  = idx & 2047;
    int s  = r >> 6, c = r & 63;
    float v = 0.f;
    if (t - 2 + kt >= 0)
      v = x[((size_t)(bt - 2 + kt) * N_ + n0 + s) * C_ + c];
    lx[kt][s][c] = f2bf(v);
  }
  __syncthreads();

  const int s = tid >> 3, g = tid & 7, co0 = g * 16;
  float acc[16];
  #pragma unroll
  for (int i = 0; i < 16; ++i) acc[i] = 0.f;

  conv_main(lx, w, s, co0, acc);

  #pragma unroll
  for (int i = 0; i < 16; ++i) acc[i] += bias[co0 + i];

  float qv[16];
  #pragma unroll
  for (int i = 0; i < 16; ++i) qv[i] = __shfl_xor(acc[i], 4);

  if (g < 4){
    unsigned short hb[16];
    #pragma unroll
    for (int i = 0; i < 16; ++i){
      float xv = bf2f(lx[2][s][co0 + i]);
      float h  = (acc[i] + xv) * sigmoidf_(qv[i]);
      hb[i] = f2bf(h);
      shh[s][co0 + i] = hb[i];
    }
    s16x8 o0, o1;
    #pragma unroll
    for (int i = 0; i < 8; ++i){ o0[i] = (short)hb[i]; o1[i] = (short)hb[8 + i]; }
    s16x8* dst = (s16x8*)&h1[((size_t)bt * N_ + n0 + s) * C_ + co0];
    dst[0] = o0; dst[1] = o1;
  }
  __syncthreads();

  { // transposed write: h1T[bt][c][n]
    int c = tid >> 2, oct = tid & 3;
    s16x8 o;
    #pragma unroll
    for (int k2 = 0; k2 < 8; ++k2) o[k2] = (short)shh[oct * 8 + k2][c];
    *(s16x8*)&h1T[((size_t)bt * C_ + c) * N_ + n0 + oct * 8] = o;
  }
}

// ---------------- GEMM: DT[bt][c][n] = (A(2048x2048) . S)^T, S given as ST[bt][c][m] ----------------
__global__ __launch_bounds__(256) void k_gemm(
    const unsigned short* __restrict__ Abf,
    const unsigned short* __restrict__ ST,
    unsigned short* __restrict__ DT)
{
  __shared__ unsigned short la[256][72];
  __shared__ unsigned short lb[64][72];
  const int tid = threadIdx.x;
  const int bt = blockIdx.y;
  const int n0 = blockIdx.x * 256;
  const int lane = tid & 63, w = tid >> 6;
  const size_t sbase = (size_t)bt * C_ * N_;

  f32x4 acc[4][4];
  #pragma unroll
  for (int a = 0; a < 4; ++a)
    #pragma unroll
    for (int b = 0; b < 4; ++b)
      acc[a][b] = (f32x4){0.f, 0.f, 0.f, 0.f};

  const int ar = tid >> 3, ac = (tid & 7) * 8;   // staging: row base / 8-elem col

  s16x8 va[8], vb[2];
  #pragma unroll
  for (int c = 0; c < 8; ++c)
    va[c] = *(const s16x8*)&Abf[(size_t)(n0 + ar + c * 32) * N_ + ac];
  #pragma unroll
  for (int c = 0; c < 2; ++c)
    vb[c] = *(const s16x8*)&ST[sbase + (size_t)(ar + c * 32) * N_ + ac];

  for (int k0 = 0; k0 < N_; k0 += 64){
    __syncthreads();
    #pragma unroll
    for (int c = 0; c < 8; ++c) *(s16x8*)&la[ar + c * 32][ac] = va[c];
    #pragma unroll
    for (int c = 0; c < 2; ++c) *(s16x8*)&lb[ar + c * 32][ac] = vb[c];
    __syncthreads();

    int k1 = k0 + 64;
    if (k1 < N_){
      #pragma unroll
      for (int c = 0; c < 8; ++c)
        va[c] = *(const s16x8*)&Abf[(size_t)(n0 + ar + c * 32) * N_ + k1 + ac];
      #pragma unroll
      for (int c = 0; c < 2; ++c)
        vb[c] = *(const s16x8*)&ST[sbase + (size_t)(ar + c * 32) * N_ + k1 + ac];
    }

    #pragma unroll
    for (int kk = 0; kk < 64; kk += 32){
      const int ko = kk + ((lane >> 4) << 3);
      s16x8 af[4], bfr[4];
      #pragma unroll
      for (int mi = 0; mi < 4; ++mi)
        af[mi] = *(const s16x8*)&la[w * 64 + mi * 16 + (lane & 15)][ko];
      #pragma unroll
      for (int ci = 0; ci < 4; ++ci)
        bfr[ci] = *(const s16x8*)&lb[ci * 16 + (lane & 15)][ko];
      #pragma unroll
      for (int mi = 0; mi < 4; ++mi)
        #pragma unroll
        for (int ci = 0; ci < 4; ++ci)
          acc[mi][ci] = __builtin_amdgcn_mfma_f32_16x16x32_bf16(af[mi], bfr[ci], acc[mi][ci], 0, 0, 0);
    }
  }

  #pragma unroll
  for (int ci = 0; ci < 4; ++ci){
    const int c = ci * 16 + (lane & 15);
    #pragma unroll
    for (int mi = 0; mi < 4; ++mi){
      const int n = n0 + w * 64 + mi * 16 + ((lane >> 4) << 2);
      s16x4 o;
      #pragma unroll
      for (int j = 0; j < 4; ++j) o[j] = (short)f2bf(acc[mi][ci][j]);
      *(s16x4*)&DT[sbase + (size_t)c * N_ + n] = o;
    }
  }
}

// ---------------- cheb combine: h2 = h1*wA + AX*wB + Z*wC + b (in-place over h1) ----------------
__global__ __launch_bounds__(256) void k_cheb(
    const unsigned short* h1,
    const unsigned short* __restrict__ AXT,
    const unsigned short* __restrict__ ZT,
    const float* __restrict__ wABC,
    const float* __restrict__ chb,
    unsigned short* h2out)
{
  __shared__ unsigned short lh[64][72];
  __shared__ unsigned short lax[64][72];
  __shared__ unsigned short lz[64][72];
  __shared__ float lw[3][64][64];
  const int tid = threadIdx.x;
  const int bt = blockIdx.y, n0 = blockIdx.x * 64;
  const size_t hb = (size_t)bt * N_ * C_;
  const size_t tb = (size_t)bt * C_ * N_;

  #pragma unroll
  for (int k = 0; k < 12; ++k)
    ((float4*)lw)[tid + k * 256] = ((const float4*)wABC)[tid + k * 256];

  const int ar = tid >> 3, ac = (tid & 7) * 8;
  #pragma unroll
  for (int c = 0; c < 2; ++c){
    int r = ar + c * 32;
    *(s16x8*)&lh[r][ac]  = *(const s16x8*)&h1[hb + (size_t)(n0 + r) * C_ + ac];
    *(s16x8*)&lax[r][ac] = *(const s16x8*)&AXT[tb + (size_t)r * N_ + n0 + ac];
    *(s16x8*)&lz[r][ac]  = *(const s16x8*)&ZT[tb + (size_t)r * N_ + n0 + ac];
  }
  __syncthreads();

  const int n = tid >> 2, c0 = (tid & 3) * 16;
  float acc[16];
  #pragma unroll
  for (int i = 0; i < 16; ++i) acc[i] = chb[c0 + i];

  for (int i = 0; i < 64; ++i){
    float hv = bf2f(lh[n][i]);
    float av = bf2f(lax[i][n]);
    float zv = bf2f(lz[i][n]);
    const float4* wa = (const float4*)&lw[0][i][c0];
    const float4* wb = (const float4*)&lw[1][i][c0];
    const float4* wc = (const float4*)&lw[2][i][c0];
    #pragma unroll
    for (int q = 0; q < 4; ++q){
      float4 a4 = wa[q], b4 = wb[q], c4 = wc[q];
      acc[q*4+0] += hv * a4.x + av * b4.x + zv * c4.x;
      acc[q*4+1] += hv * a4.y + av * b4.y + zv * c4.y;
      acc[q*4+2] += hv * a4.z + av * b4.z + zv * c4.z;
      acc[q*4+3] += hv * a4.w + av * b4.w + zv * c4.w;
    }
  }

  s16x8 o0, o1;
  #pragma unroll
  for (int i = 0; i < 8; ++i){ o0[i] = (short)f2bf(acc[i]); o1[i] = (short)f2bf(acc[8 + i]); }
  s16x8* dst = (s16x8*)&h2out[hb + (size_t)(n0 + n) * C_ + c0];
  dst[0] = o0; dst[1] = o1;
}

// ---------------- conv2 + GLU + LayerNorm -> out (f32) ----------------
__global__ __launch_bounds__(256) void k_conv2_ln(
    const unsigned short* __restrict__ h2, const float* __restrict__ w,
    const float* __restrict__ bias, const float* __restrict__ lng,
    const float* __restrict__ lnb, float* __restrict__ out)
{
  __shared__ unsigned short lx[3][32][72];
  const int tid = threadIdx.x;
  const int bt = blockIdx.y, t = bt & 31;
  const int n0 = blockIdx.x * 32;

  #pragma unroll
  for (int k = 0; k < 24; ++k){
    int idx = tid + k * 256;
    int kt = idx >> 11;
    int r  = idx & 2047;
    int s  = r >> 6, c = r & 63;
    unsigned short v = 0;
    if (t - 2 + kt >= 0)
      v = h2[((size_t)(bt - 2 + kt) * N_ + n0 + s) * C_ + c];
    lx[kt][s][c] = v;
  }
  __syncthreads();

  const int s = tid >> 3, g = tid & 7, co0 = g * 16;
  float acc[16];
  #pragma unroll
  for (int i = 0; i < 16; ++i) acc[i] = 0.f;

  conv_main(lx, w, s, co0, acc);

  #pragma unroll
  for (int i = 0; i < 16; ++i) acc[i] += bias[co0 + i];

  float qv[16];
  #pragma unroll
  for (int i = 0; i < 16; ++i) qv[i] = __shfl_xor(acc[i], 4);

  if (g < 4){
    float h[16];
    float sm = 0.f, sq = 0.f;
    #pragma unroll
    for (int i = 0; i < 16; ++i){
      float xv = bf2f(lx[2][s][co0 + i]);
      h[i] = (acc[i] + xv) * sigmoidf_(qv[i]);
      sm += h[i]; sq += h[i] * h[i];
    }
    sm += __shfl_xor(sm, 1); sq += __shfl_xor(sq, 1);
    sm += __shfl_xor(sm, 2); sq += __shfl_xor(sq, 2);
    float mu  = sm * (1.f / 64.f);
    float var = sq * (1.f / 64.f) - mu * mu;
    float rs  = rsqrtf(var + 1e-5f);
    float4* d4 = (float4*)&out[((size_t)bt * N_ + n0 + s) * C_ + co0];
    #pragma unroll
    for (int q = 0; q < 4; ++q){
      float4 o;
      o.x = (h[q*4+0] - mu) * rs * lng[co0 + q*4+0] + lnb[co0 + q*4+0];
      o.y = (h[q*4+1] - mu) * rs * lng[co0 + q*4+1] + lnb[co0 + q*4+1];
      o.z = (h[q*4+2] - mu) * rs * lng[co0 + q*4+2] + lnb[co0 + q*4+2];
      o.w = (h[q*4+3] - mu) * rs * lng[co0 + q*4+3] + lnb[co0 + q*4+3];
      d4[q] = o;
    }
  }
}

extern "C" void kernel_launch(void* const* d_in, const int* in_sizes, int n_in,
                              void* d_out, int out_size, void* d_ws, size_t ws_size,
                              hipStream_t stream)
{
  const float* x   = (const float*)d_in[0];
  const float* A   = (const float*)d_in[1];
  const float* c1w = (const float*)d_in[2];
  const float* c1b = (const float*)d_in[3];
  const float* chw = (const float*)d_in[4];
  const float* chb = (const float*)d_in[5];
  const float* c2w = (const float*)d_in[6];
  const float* c2b = (const float*)d_in[7];
  const float* lng = (const float*)d_in[8];
  const float* lnb = (const float*)d_in[9];
  float* out = (float*)d_out;

  char* ws = (char*)d_ws;
  unsigned short* h1  = (unsigned short*)ws;                      // 67,108,864 B (h1, then h2 in-place)
  unsigned short* Abf = (unsigned short*)(ws + 67108864);         //  8,388,608 B
  float* wABC         = (float*)(ws + 67108864 + 8388608);        //     49,152 B
  // d_out doubles as scratch until the final kernel:
  unsigned short* h1T = (unsigned short*)d_out;                   // 67,108,864 B
  unsigned short* AXT = (unsigned short*)((char*)d_out + 67108864); // 67,108,864 B
  unsigned short* ZT  = h1T;                                      // reuse after GEMM1

  k_prep_A<<<4096, 256, 0, stream>>>(A, Abf);
  k_prep_w<<<16, 256, 0, stream>>>(chw, wABC);
  k_conv1<<<dim3(64, 256), 256, 0, stream>>>(x, c1w, c1b, h1, h1T);
  k_gemm<<<dim3(8, 256), 256, 0, stream>>>(Abf, h1T, AXT);   // AX^T
  k_gemm<<<dim3(8, 256), 256, 0, stream>>>(Abf, AXT, ZT);    // (A*AX)^T
  k_cheb<<<dim3(32, 256), 256, 0, stream>>>(h1, AXT, ZT, wABC, chb, h1); // h2 in-place
  k_conv2_ln<<<dim3(64, 256), 256, 0, stream>>>(h1, c2w, c2b, lng, lnb, out);
}

// Round 2
// 1026.512 us; speedup vs baseline: 6.1128x; 6.1128x over previous
//
#include <hip/hip_runtime.h>
#include <stdint.h>

#define B_ 8
#define T_ 32
#define N_ 2048
#define C_ 64

typedef __attribute__((ext_vector_type(4))) float f32x4;
typedef __attribute__((ext_vector_type(8))) short s16x8;
typedef __attribute__((ext_vector_type(4))) short s16x4;

static __device__ __forceinline__ unsigned short f2bf(float f){
  union { float f; unsigned u; } v; v.f = f;
  unsigned u = v.u;
  return (unsigned short)((u + 0x7FFFu + ((u >> 16) & 1u)) >> 16);
}
static __device__ __forceinline__ float bf2f(unsigned short h){
  union { unsigned u; float f; } v; v.u = ((unsigned)h) << 16;
  return v.f;
}
static __device__ __forceinline__ float sigmoidf_(float x){
  return 1.f / (1.f + __expf(-x));
}

// ---------------- prep ----------------
__global__ __launch_bounds__(256) void k_prep_A(const float* __restrict__ A,
                                                unsigned short* __restrict__ Abf){
  int i = blockIdx.x * 256 + threadIdx.x;       // float4 index, 1048576 total
  float4 v = ((const float4*)A)[i];
  s16x4 o;
  o[0] = (short)f2bf(v.x); o[1] = (short)f2bf(v.y);
  o[2] = (short)f2bf(v.z); o[3] = (short)f2bf(v.w);
  ((s16x4*)Abf)[i] = o;
}

// wA = w0 - w2, wB = -w1, wC = 2*w2   (each 64x64 f32)
__global__ __launch_bounds__(256) void k_prep_w(const float* __restrict__ chw,
                                                float* __restrict__ wABC){
  int i = blockIdx.x * 256 + threadIdx.x;       // 0..4095
  float a = chw[i], b = chw[4096 + i], c = chw[8192 + i];
  wABC[i]        = a - c;
  wABC[4096 + i] = -b;
  wABC[8192 + i] = 2.f * c;
}

// wT[co][kt*64+ci] = w[kt][ci][co]  (bf16, [128][192]) for both convs
__global__ __launch_bounds__(256) void k_prep_wt(const float* __restrict__ c1w,
                                                 const float* __restrict__ c2w,
                                                 unsigned short* __restrict__ wT1,
                                                 unsigned short* __restrict__ wT2){
  int idx = blockIdx.x * 256 + threadIdx.x;     // 0..49151
  const float* src = c1w;
  unsigned short* dst = wT1;
  int rem = idx;
  if (rem >= 24576){ rem -= 24576; src = c2w; dst = wT2; }
  int co = rem / 192;
  int k  = rem - co * 192;
  int kt = k >> 6, ci = k & 63;
  dst[co * 192 + k] = f2bf(src[kt * 8192 + ci * 128 + co]);
}

// ---------------- conv1 (MFMA implicit GEMM) + GLU -> h1, h1T ----------------
__global__ __launch_bounds__(256) void k_conv1_mfma(
    const float* __restrict__ x, const unsigned short* __restrict__ wT,
    const float* __restrict__ bias,
    unsigned short* __restrict__ h1, unsigned short* __restrict__ h1T)
{
  __shared__ unsigned short la[64][200];   // A tile: [row][kt*64+ci]
  __shared__ unsigned short lb[128][200];  // B tile: [co][k]
  const int tid = threadIdx.x;
  const int bt = blockIdx.y, t = bt & 31;
  const int n0 = blockIdx.x * 64;
  const int lane = tid & 63, wv = tid >> 6;
  const int l15 = lane & 15, lh = lane >> 4;
  const int wrow0 = wv * 16;

  { // stage weights: 2 threads per row, 12 x 16B each
    int co = tid >> 1, hf = tid & 1;
    const s16x8* src = (const s16x8*)&wT[co * 192 + hf * 96];
    #pragma unroll
    for (int i = 0; i < 12; ++i)
      *(s16x8*)&lb[co][hf * 96 + i * 8] = src[i];
  }
  // stage A: 3 time slices, f32 -> bf16, zero-pad t<2 boundary
  #pragma unroll
  for (int it = 0; it < 6; ++it){
    int idx = it * 256 + tid;                 // 0..1535
    int kt = idx >> 9, rem = idx & 511;
    int row = rem >> 3, c8 = (rem & 7) * 8;
    s16x8 o = {0,0,0,0,0,0,0,0};
    if (t + kt >= 2){
      const float4* src = (const float4*)&x[(((size_t)(bt - 2 + kt)) * N_ + n0 + row) * C_ + c8];
      float4 v0 = src[0], v1 = src[1];
      o[0]=(short)f2bf(v0.x); o[1]=(short)f2bf(v0.y); o[2]=(short)f2bf(v0.z); o[3]=(short)f2bf(v0.w);
      o[4]=(short)f2bf(v1.x); o[5]=(short)f2bf(v1.y); o[6]=(short)f2bf(v1.z); o[7]=(short)f2bf(v1.w);
    }
    *(s16x8*)&la[row][kt * 64 + c8] = o;
  }
  __syncthreads();

  f32x4 acc[8];
  #pragma unroll
  for (int i = 0; i < 8; ++i) acc[i] = (f32x4){0.f,0.f,0.f,0.f};

  #pragma unroll
  for (int ks = 0; ks < 6; ++ks){
    const int ko = ks * 32 + lh * 8;
    s16x8 af = *(const s16x8*)&la[wrow0 + l15][ko];
    #pragma unroll
    for (int ct = 0; ct < 8; ++ct){
      s16x8 bfv = *(const s16x8*)&lb[ct * 16 + l15][ko];
      acc[ct] = __builtin_amdgcn_mfma_f32_16x16x32_bf16(af, bfv, acc[ct], 0, 0, 0);
    }
  }

  // GLU epilogue: P = cols 0..63 (+x residual), Q = cols 64..127, same lane pairs
  float hv[4][4];
  #pragma unroll
  for (int ct = 0; ct < 4; ++ct){
    int col = ct * 16 + l15;
    float bp = bias[col], bq = bias[64 + col];
    #pragma unroll
    for (int j = 0; j < 4; ++j){
      int row = lh * 4 + j;
      float P = acc[ct][j] + bp;
      float Q = acc[ct + 4][j] + bq;
      float xv = bf2f(la[wrow0 + row][128 + col]);   // kt=2 slice = x[bt]
      hv[ct][j] = (P + xv) * sigmoidf_(Q);
    }
  }
  __syncthreads();                                   // done reading la
  unsigned short (*sh)[72] = (unsigned short(*)[72])la;
  #pragma unroll
  for (int ct = 0; ct < 4; ++ct)
    #pragma unroll
    for (int j = 0; j < 4; ++j)
      sh[wrow0 + lh * 4 + j][ct * 16 + l15] = f2bf(hv[ct][j]);
  __syncthreads();

  { // coalesced h1 write
    int row = tid >> 2, cs = (tid & 3) * 16;
    s16x8 o0, o1;
    #pragma unroll
    for (int i = 0; i < 8; ++i){ o0[i] = (short)sh[row][cs + i]; o1[i] = (short)sh[row][cs + 8 + i]; }
    s16x8* dst = (s16x8*)&h1[((size_t)bt * N_ + n0 + row) * C_ + cs];
    dst[0] = o0; dst[1] = o1;
  }
  { // transposed h1T write
    int c = tid >> 2, r0 = (tid & 3) * 16;
    s16x8 o0, o1;
    #pragma unroll
    for (int k = 0; k < 8; ++k){ o0[k] = (short)sh[r0 + k][c]; o1[k] = (short)sh[r0 + 8 + k][c]; }
    size_t base = ((size_t)bt * C_ + c) * N_ + n0 + r0;
    *(s16x8*)&h1T[base] = o0;
    *(s16x8*)&h1T[base + 8] = o1;
  }
}

// ---------------- conv2 (MFMA) + GLU + LayerNorm -> out (f32) ----------------
__global__ __launch_bounds__(256) void k_conv2_ln_mfma(
    const unsigned short* __restrict__ h2, const unsigned short* __restrict__ wT,
    const float* __restrict__ bias, const float* __restrict__ lng,
    const float* __restrict__ lnb, float* __restrict__ out)
{
  __shared__ unsigned short la[64][200];
  __shared__ unsigned short lb[128][200];
  const int tid = threadIdx.x;
  const int bt = blockIdx.y, t = bt & 31;
  const int n0 = blockIdx.x * 64;
  const int lane = tid & 63, wv = tid >> 6;
  const int l15 = lane & 15, lh = lane >> 4;
  const int wrow0 = wv * 16;

  {
    int co = tid >> 1, hf = tid & 1;
    const s16x8* src = (const s16x8*)&wT[co * 192 + hf * 96];
    #pragma unroll
    for (int i = 0; i < 12; ++i)
      *(s16x8*)&lb[co][hf * 96 + i * 8] = src[i];
  }
  #pragma unroll
  for (int it = 0; it < 6; ++it){
    int idx = it * 256 + tid;
    int kt = idx >> 9, rem = idx & 511;
    int row = rem >> 3, c8 = (rem & 7) * 8;
    s16x8 o = {0,0,0,0,0,0,0,0};
    if (t + kt >= 2)
      o = *(const s16x8*)&h2[(((size_t)(bt - 2 + kt)) * N_ + n0 + row) * C_ + c8];
    *(s16x8*)&la[row][kt * 64 + c8] = o;
  }
  __syncthreads();

  f32x4 acc[8];
  #pragma unroll
  for (int i = 0; i < 8; ++i) acc[i] = (f32x4){0.f,0.f,0.f,0.f};

  #pragma unroll
  for (int ks = 0; ks < 6; ++ks){
    const int ko = ks * 32 + lh * 8;
    s16x8 af = *(const s16x8*)&la[wrow0 + l15][ko];
    #pragma unroll
    for (int ct = 0; ct < 8; ++ct){
      s16x8 bfv = *(const s16x8*)&lb[ct * 16 + l15][ko];
      acc[ct] = __builtin_amdgcn_mfma_f32_16x16x32_bf16(af, bfv, acc[ct], 0, 0, 0);
    }
  }

  float hv[4][4];
  #pragma unroll
  for (int ct = 0; ct < 4; ++ct){
    int col = ct * 16 + l15;
    float bp = bias[col], bq = bias[64 + col];
    #pragma unroll
    for (int j = 0; j < 4; ++j){
      int row = lh * 4 + j;
      float P = acc[ct][j] + bp;
      float Q = acc[ct + 4][j] + bq;
      float xv = bf2f(la[wrow0 + row][128 + col]);
      hv[ct][j] = (P + xv) * sigmoidf_(Q);
    }
  }

  // LayerNorm per row: row lives in one 16-lane group (4 ct values per lane)
  #pragma unroll
  for (int j = 0; j < 4; ++j){
    float sm = hv[0][j] + hv[1][j] + hv[2][j] + hv[3][j];
    float sq = hv[0][j]*hv[0][j] + hv[1][j]*hv[1][j] + hv[2][j]*hv[2][j] + hv[3][j]*hv[3][j];
    sm += __shfl_xor(sm, 1); sq += __shfl_xor(sq, 1);
    sm += __shfl_xor(sm, 2); sq += __shfl_xor(sq, 2);
    sm += __shfl_xor(sm, 4); sq += __shfl_xor(sq, 4);
    sm += __shfl_xor(sm, 8); sq += __shfl_xor(sq, 8);
    float mu  = sm * (1.f / 64.f);
    float var = sq * (1.f / 64.f) - mu * mu;
    float rs  = rsqrtf(var + 1e-5f);
    int row = wrow0 + lh * 4 + j;
    size_t base = ((size_t)bt * N_ + n0 + row) * C_;
    #pragma unroll
    for (int ct = 0; ct < 4; ++ct){
      int col = ct * 16 + l15;
      out[base + col] = (hv[ct][j] - mu) * rs * lng[col] + lnb[col];
    }
  }
}

// ---------------- GEMM: DT[bt][c][n] = (A(2048x2048) . S)^T, S given as ST[bt][c][m] ----------------
__global__ __launch_bounds__(256) void k_gemm(
    const unsigned short* __restrict__ Abf,
    const unsigned short* __restrict__ ST,
    unsigned short* __restrict__ DT)
{
  __shared__ unsigned short la[256][72];
  __shared__ unsigned short lb[64][72];
  const int tid = threadIdx.x;
  const int bt = blockIdx.y;
  const int n0 = blockIdx.x * 256;
  const int lane = tid & 63, w = tid >> 6;
  const size_t sbase = (size_t)bt * C_ * N_;

  f32x4 acc[4][4];
  #pragma unroll
  for (int a = 0; a < 4; ++a)
    #pragma unroll
    for (int b = 0; b < 4; ++b)
      acc[a][b] = (f32x4){0.f, 0.f, 0.f, 0.f};

  const int ar = tid >> 3, ac = (tid & 7) * 8;   // staging: row base / 8-elem col

  s16x8 va[8], vb[2];
  #pragma unroll
  for (int c = 0; c < 8; ++c)
    va[c] = *(const s16x8*)&Abf[(size_t)(n0 + ar + c * 32) * N_ + ac];
  #pragma unroll
  for (int c = 0; c < 2; ++c)
    vb[c] = *(const s16x8*)&ST[sbase + (size_t)(ar + c * 32) * N_ + ac];

  for (int k0 = 0; k0 < N_; k0 += 64){
    __syncthreads();
    #pragma unroll
    for (int c = 0; c < 8; ++c) *(s16x8*)&la[ar + c * 32][ac] = va[c];
    #pragma unroll
    for (int c = 0; c < 2; ++c) *(s16x8*)&lb[ar + c * 32][ac] = vb[c];
    __syncthreads();

    int k1 = k0 + 64;
    if (k1 < N_){
      #pragma unroll
      for (int c = 0; c < 8; ++c)
        va[c] = *(const s16x8*)&Abf[(size_t)(n0 + ar + c * 32) * N_ + k1 + ac];
      #pragma unroll
      for (int c = 0; c < 2; ++c)
        vb[c] = *(const s16x8*)&ST[sbase + (size_t)(ar + c * 32) * N_ + k1 + ac];
    }

    #pragma unroll
    for (int kk = 0; kk < 64; kk += 32){
      const int ko = kk + ((lane >> 4) << 3);
      s16x8 af[4], bfr[4];
      #pragma unroll
      for (int mi = 0; mi < 4; ++mi)
        af[mi] = *(const s16x8*)&la[w * 64 + mi * 16 + (lane & 15)][ko];
      #pragma unroll
      for (int ci = 0; ci < 4; ++ci)
        bfr[ci] = *(const s16x8*)&lb[ci * 16 + (lane & 15)][ko];
      #pragma unroll
      for (int mi = 0; mi < 4; ++mi)
        #pragma unroll
        for (int ci = 0; ci < 4; ++ci)
          acc[mi][ci] = __builtin_amdgcn_mfma_f32_16x16x32_bf16(af[mi], bfr[ci], acc[mi][ci], 0, 0, 0);
    }
  }

  #pragma unroll
  for (int ci = 0; ci < 4; ++ci){
    const int c = ci * 16 + (lane & 15);
    #pragma unroll
    for (int mi = 0; mi < 4; ++mi){
      const int n = n0 + w * 64 + mi * 16 + ((lane >> 4) << 2);
      s16x4 o;
      #pragma unroll
      for (int j = 0; j < 4; ++j) o[j] = (short)f2bf(acc[mi][ci][j]);
      *(s16x4*)&DT[sbase + (size_t)c * N_ + n] = o;
    }
  }
}

// ---------------- cheb combine: h2 = h1*wA + AX*wB + Z*wC + b (in-place over h1) ----------------
__global__ __launch_bounds__(256) void k_cheb(
    const unsigned short* h1,
    const unsigned short* __restrict__ AXT,
    const unsigned short* __restrict__ ZT,
    const float* __restrict__ wABC,
    const float* __restrict__ chb,
    unsigned short* h2out)
{
  __shared__ unsigned short lh[64][72];
  __shared__ unsigned short lax[64][72];
  __shared__ unsigned short lz[64][72];
  __shared__ float lw[3][64][64];
  const int tid = threadIdx.x;
  const int bt = blockIdx.y, n0 = blockIdx.x * 64;
  const size_t hb = (size_t)bt * N_ * C_;
  const size_t tb = (size_t)bt * C_ * N_;

  #pragma unroll
  for (int k = 0; k < 12; ++k)
    ((float4*)lw)[tid + k * 256] = ((const float4*)wABC)[tid + k * 256];

  const int ar = tid >> 3, ac = (tid & 7) * 8;
  #pragma unroll
  for (int c = 0; c < 2; ++c){
    int r = ar + c * 32;
    *(s16x8*)&lh[r][ac]  = *(const s16x8*)&h1[hb + (size_t)(n0 + r) * C_ + ac];
    *(s16x8*)&lax[r][ac] = *(const s16x8*)&AXT[tb + (size_t)r * N_ + n0 + ac];
    *(s16x8*)&lz[r][ac]  = *(const s16x8*)&ZT[tb + (size_t)r * N_ + n0 + ac];
  }
  __syncthreads();

  const int n = tid >> 2, c0 = (tid & 3) * 16;
  float acc[16];
  #pragma unroll
  for (int i = 0; i < 16; ++i) acc[i] = chb[c0 + i];

  for (int i = 0; i < 64; ++i){
    float hvv = bf2f(lh[n][i]);
    float av = bf2f(lax[i][n]);
    float zv = bf2f(lz[i][n]);
    const float4* wa = (const float4*)&lw[0][i][c0];
    const float4* wb = (const float4*)&lw[1][i][c0];
    const float4* wc = (const float4*)&lw[2][i][c0];
    #pragma unroll
    for (int q = 0; q < 4; ++q){
      float4 a4 = wa[q], b4 = wb[q], c4 = wc[q];
      acc[q*4+0] += hvv * a4.x + av * b4.x + zv * c4.x;
      acc[q*4+1] += hvv * a4.y + av * b4.y + zv * c4.y;
      acc[q*4+2] += hvv * a4.z + av * b4.z + zv * c4.z;
      acc[q*4+3] += hvv * a4.w + av * b4.w + zv * c4.w;
    }
  }

  s16x8 o0, o1;
  #pragma unroll
  for (int i = 0; i < 8; ++i){ o0[i] = (short)f2bf(acc[i]); o1[i] = (short)f2bf(acc[8 + i]); }
  s16x8* dst = (s16x8*)&h2out[hb + (size_t)(n0 + n) * C_ + c0];
  dst[0] = o0; dst[1] = o1;
}

extern "C" void kernel_launch(void* const* d_in, const int* in_sizes, int n_in,
                              void* d_out, int out_size, void* d_ws, size_t ws_size,
                              hipStream_t stream)
{
  const float* x   = (const float*)d_in[0];
  const float* A   = (const float*)d_in[1];
  const float* c1w = (const float*)d_in[2];
  const float* c1b = (const float*)d_in[3];
  const float* chw = (const float*)d_in[4];
  const float* chb = (const float*)d_in[5];
  const float* c2w = (const float*)d_in[6];
  const float* c2b = (const float*)d_in[7];
  const float* lng = (const float*)d_in[8];
  const float* lnb = (const float*)d_in[9];
  float* out = (float*)d_out;

  char* ws = (char*)d_ws;
  unsigned short* h1  = (unsigned short*)ws;                         // 67,108,864 B (h1, then h2 in-place)
  unsigned short* Abf = (unsigned short*)(ws + 67108864);            //  8,388,608 B
  float* wABC         = (float*)(ws + 75497472);                     //     49,152 B
  unsigned short* wT1 = (unsigned short*)(ws + 75546624);            //     49,152 B
  unsigned short* wT2 = (unsigned short*)(ws + 75595776);            //     49,152 B
  // d_out doubles as scratch until the final kernel:
  unsigned short* h1T = (unsigned short*)d_out;                      // 67,108,864 B
  unsigned short* AXT = (unsigned short*)((char*)d_out + 67108864);  // 67,108,864 B
  unsigned short* ZT  = h1T;                                         // reuse after GEMM1

  k_prep_A<<<4096, 256, 0, stream>>>(A, Abf);
  k_prep_w<<<16, 256, 0, stream>>>(chw, wABC);
  k_prep_wt<<<192, 256, 0, stream>>>(c1w, c2w, wT1, wT2);
  k_conv1_mfma<<<dim3(32, 256), 256, 0, stream>>>(x, wT1, c1b, h1, h1T);
  k_gemm<<<dim3(8, 256), 256, 0, stream>>>(Abf, h1T, AXT);   // AX^T
  k_gemm<<<dim3(8, 256), 256, 0, stream>>>(Abf, AXT, ZT);    // (A*AX)^T
  k_cheb<<<dim3(32, 256), 256, 0, stream>>>(h1, AXT, ZT, wABC, chb, h1); // h2 in-place
  k_conv2_ln_mfma<<<dim3(32, 256), 256, 0, stream>>>(h1, wT2, c2b, lng, lnb, out);
}